// Round 13
// baseline (1910.174 us; speedup 1.0000x reference)
//
#include <hip/hip_runtime.h>
#include <stdint.h>

// RNNTextClassifier: B=64, S=512, E=H=512, NCLS=8
// Round 16: R15 base (proven 1748us) + 2-deep PIPELINED polls.
// R15 parallelized the two MALL RTs (A waves poll in0, B waves poll h).
// R16 halves detection quantization: each spin keeps TWO load batches
// X/Y in flight; vmcnt(8|9) retires the older batch while the newer is
// still outstanding -> poll samples the line every RT/2 instead of RT.
// Self-contained region (no barrier inside; R7 hazard shape respected);
// exit path drains vmcnt(0) with both batches as asm operands before any
// register reuse; batch selection is wave-uniform (__all) -> no divergence.
// Everything else byte-identical to R15: A/B wave split, 256-thread
// stride-16 staging (2-way LDS, free), ring slot=s&3, tag=s&7, bp at s-4,
// UC sc0 sc1, launch_bounds(512,1).
// ws: hsl 1MB at offset 0 (memset to 0 each launch).

#define BB 64
#define SS 512
#define HH 512

typedef short bf16x8 __attribute__((ext_vector_type(8)));
typedef float f32x4 __attribute__((ext_vector_type(4)));
typedef int i32x4 __attribute__((ext_vector_type(4)));
typedef unsigned int u32;
typedef u32 u32x2 __attribute__((ext_vector_type(2)));

__device__ __forceinline__ unsigned short f2bf(float f) {
  uint32_t u = __builtin_bit_cast(uint32_t, f);
  u += 0x7FFFu + ((u >> 16) & 1u);
  return (unsigned short)(u >> 16);
}
__device__ __forceinline__ float bf2f(unsigned short h) {
  uint32_t u = ((uint32_t)h) << 16;
  return __builtin_bit_cast(float, u);
}
__device__ __forceinline__ int pack2(unsigned short a, unsigned short b) {
  return (int)(unsigned int)a | ((int)(unsigned int)b << 16);
}
__device__ __forceinline__ u32 hipack(u32 a, u32 b) {
  return (a >> 16) | (b & 0xFFFF0000u);
}
__device__ __forceinline__ u32 lopack(u32 a, u32 b) {
  return (a & 0xFFF8u) | ((b & 0xFFF8u) << 16);
}
__device__ __forceinline__ bool tag4(i32x4 v, u32 t) {
  u32 m = (((u32)v[0] ^ t) | ((u32)v[1] ^ t) | ((u32)v[2] ^ t) | ((u32)v[3] ^ t)) & 7u;
  return m == 0u;
}
__device__ __forceinline__ float fast_tanh(float v) {
  float a = __builtin_fabsf(v);
  float e = __expf(-2.0f * a);
  float t = (1.0f - e) / (1.0f + e);
  return __builtin_copysignf(t, v);
}

#define UC_LOAD4(dst, ptr) \
  asm volatile("global_load_dwordx4 %0, %1, off sc0 sc1" : "=v"(dst) : "v"(ptr))
#define UC_LOAD1(dst, ptr) \
  asm volatile("global_load_dword %0, %1, off sc0 sc1" : "=v"(dst) : "v"(ptr))
#define UC_STORE2(ptr, v) \
  asm volatile("global_store_dwordx2 %0, %1, off sc0 sc1" ::"v"(ptr), "v"(v) : "memory")

// issue one 8x dwordx4 batch over the lane's 4 chunks (gch+16j)
#define ISSUE8(a0, a1, a2, a3, a4, a5, a6, a7, base)  \
  do {                                                \
    UC_LOAD4(a0, (base) + 8 * gch + 0);               \
    UC_LOAD4(a1, (base) + 8 * gch + 4);               \
    UC_LOAD4(a2, (base) + 8 * gch + 128);             \
    UC_LOAD4(a3, (base) + 8 * gch + 132);             \
    UC_LOAD4(a4, (base) + 8 * gch + 256);             \
    UC_LOAD4(a5, (base) + 8 * gch + 260);             \
    UC_LOAD4(a6, (base) + 8 * gch + 384);             \
    UC_LOAD4(a7, (base) + 8 * gch + 388);             \
  } while (0)

#define TAGOK8(a0, a1, a2, a3, a4, a5, a6, a7, t)                         \
  (tag4(a0, t) && tag4(a1, t) && tag4(a2, t) && tag4(a3, t) &&            \
   tag4(a4, t) && tag4(a5, t) && tag4(a6, t) && tag4(a7, t))

// stage hi halves into swizzled s_in0 (chunks gch+16j)
#define STAGE_IN0(w0, w1, w2, w3, w4, w5, w6, w7)                          \
  do {                                                                     \
    i32x4 A;                                                               \
    A[0] = (int)hipack(w0[0], w0[1]); A[1] = (int)hipack(w0[2], w0[3]);    \
    A[2] = (int)hipack(w1[0], w1[1]); A[3] = (int)hipack(w1[2], w1[3]);    \
    *(i32x4*)(s_in0 + gr * 512 + (((gch + 0) ^ (gr & 7)) << 3)) = A;       \
    A[0] = (int)hipack(w2[0], w2[1]); A[1] = (int)hipack(w2[2], w2[3]);    \
    A[2] = (int)hipack(w3[0], w3[1]); A[3] = (int)hipack(w3[2], w3[3]);    \
    *(i32x4*)(s_in0 + gr * 512 + (((gch + 16) ^ (gr & 7)) << 3)) = A;      \
    A[0] = (int)hipack(w4[0], w4[1]); A[1] = (int)hipack(w4[2], w4[3]);    \
    A[2] = (int)hipack(w5[0], w5[1]); A[3] = (int)hipack(w5[2], w5[3]);    \
    *(i32x4*)(s_in0 + gr * 512 + (((gch + 32) ^ (gr & 7)) << 3)) = A;      \
    A[0] = (int)hipack(w6[0], w6[1]); A[1] = (int)hipack(w6[2], w6[3]);    \
    A[2] = (int)hipack(w7[0], w7[1]); A[3] = (int)hipack(w7[2], w7[3]);    \
    *(i32x4*)(s_in0 + gr * 512 + (((gch + 48) ^ (gr & 7)) << 3)) = A;      \
  } while (0)

// stage H hi/lo into swizzled s_Hhi/s_Hlo (chunks gch+16j)
#define STAGE_H(w0, w1, w2, w3, w4, w5, w6, w7)                            \
  do {                                                                     \
    i32x4 A, B;                                                            \
    A[0] = (int)hipack(w0[0], w0[1]); A[1] = (int)hipack(w0[2], w0[3]);    \
    A[2] = (int)hipack(w1[0], w1[1]); A[3] = (int)hipack(w1[2], w1[3]);    \
    B[0] = (int)lopack(w0[0], w0[1]); B[1] = (int)lopack(w0[2], w0[3]);    \
    B[2] = (int)lopack(w1[0], w1[1]); B[3] = (int)lopack(w1[2], w1[3]);    \
    *(i32x4*)(s_Hhi + gr * 512 + (((gch + 0) ^ (gr & 7)) << 3)) = A;       \
    *(i32x4*)(s_Hlo + gr * 512 + (((gch + 0) ^ (gr & 7)) << 3)) = B;       \
    A[0] = (int)hipack(w2[0], w2[1]); A[1] = (int)hipack(w2[2], w2[3]);    \
    A[2] = (int)hipack(w3[0], w3[1]); A[3] = (int)hipack(w3[2], w3[3]);    \
    B[0] = (int)lopack(w2[0], w2[1]); B[1] = (int)lopack(w2[2], w2[3]);    \
    B[2] = (int)lopack(w3[0], w3[1]); B[3] = (int)lopack(w3[2], w3[3]);    \
    *(i32x4*)(s_Hhi + gr * 512 + (((gch + 16) ^ (gr & 7)) << 3)) = A;      \
    *(i32x4*)(s_Hlo + gr * 512 + (((gch + 16) ^ (gr & 7)) << 3)) = B;      \
    A[0] = (int)hipack(w4[0], w4[1]); A[1] = (int)hipack(w4[2], w4[3]);    \
    A[2] = (int)hipack(w5[0], w5[1]); A[3] = (int)hipack(w5[2], w5[3]);    \
    B[0] = (int)lopack(w4[0], w4[1]); B[1] = (int)lopack(w4[2], w4[3]);    \
    B[2] = (int)lopack(w5[0], w5[1]); B[3] = (int)lopack(w5[2], w5[3]);    \
    *(i32x4*)(s_Hhi + gr * 512 + (((gch + 32) ^ (gr & 7)) << 3)) = A;      \
    *(i32x4*)(s_Hlo + gr * 512 + (((gch + 32) ^ (gr & 7)) << 3)) = B;      \
    A[0] = (int)hipack(w6[0], w6[1]); A[1] = (int)hipack(w6[2], w6[3]);    \
    A[2] = (int)hipack(w7[0], w7[1]); A[3] = (int)hipack(w7[2], w7[3]);    \
    B[0] = (int)lopack(w6[0], w6[1]); B[1] = (int)lopack(w6[2], w6[3]);    \
    B[2] = (int)lopack(w7[0], w7[1]); B[3] = (int)lopack(w7[2], w7[3]);    \
    *(i32x4*)(s_Hhi + gr * 512 + (((gch + 48) ^ (gr & 7)) << 3)) = A;      \
    *(i32x4*)(s_Hlo + gr * 512 + (((gch + 48) ^ (gr & 7)) << 3)) = B;      \
  } while (0)

__global__ __launch_bounds__(512, 1) void k_rnn(
    const int* __restrict__ x, const float* __restrict__ emb,
    const float* __restrict__ Wih0, const float* __restrict__ Whh0,
    const float* __restrict__ bih0, const float* __restrict__ bhh0,
    const float* __restrict__ Wih1, const float* __restrict__ Whh1,
    const float* __restrict__ bih1, const float* __restrict__ bhh1,
    u32* __restrict__ hsl) {
  const int tid = threadIdx.x;
  const int bid = blockIdx.x;
  const int layer = bid >> 5;  // 0 or 1
  const int lb = bid & 31;
  const int bg = lb >> 3;  // batch group (16 rows)
  const int c = lb & 7;    // hidden slice (64 dims)
  const int wid = tid >> 6;
  const int lane = tid & 63;
  const int kq = wid >> 1;  // K-quarter (0..3)
  const int nh = wid & 1;   // N-half (32 cols)
  // staging-group index: A = waves 0..3, B = waves 4..7
  const int gt = tid & 255;
  const int gr = gt >> 4;   // row 0..15
  const int gch = gt & 15;  // chunk-base 0..15 (chunks gch+16j, j=0..3)

  __shared__ __align__(16) unsigned short s_in0[16 * 512];
  __shared__ __align__(16) unsigned short s_Hhi[16 * 512];
  __shared__ __align__(16) unsigned short s_Hlo[16 * 512];
  __shared__ __align__(16) float s_part[4 * 16 * 64];

  const float* Wih = layer ? Wih1 : Wih0;
  const float* Whh = layer ? Whh1 : Whh0;
  const float* bi = layer ? bih1 : bih0;
  const float* bh = layer ? bhh1 : bhh0;

  // ---- one-time: W fragments into VGPRs (mapping unchanged from R8) ----
  bf16x8 wih[2][4], whhh[2][4], whhl[2][4];
  {
    const int r16 = lane & 15, kg = lane >> 4;
#pragma unroll
    for (int nt = 0; nt < 2; ++nt) {
#pragma unroll
      for (int kt = 0; kt < 4; ++kt) {
        int row = c * 64 + nh * 32 + nt * 16 + r16;
        int k0 = kq * 128 + kt * 32 + kg * 8;
        const float* p = Wih + row * 512 + k0;
        bf16x8 v;
#pragma unroll
        for (int j = 0; j < 8; ++j) v[j] = (short)f2bf(p[j]);
        wih[nt][kt] = v;
        const float* q = Whh + row * 512 + k0;
        bf16x8 vh, vl;
#pragma unroll
        for (int j = 0; j < 8; ++j) {
          float f = q[j];
          unsigned short h = f2bf(f);
          vh[j] = (short)h;
          vl[j] = (short)f2bf(f - bf2f(h));
        }
        whhh[nt][kt] = vh;
        whhl[nt][kt] = vl;
      }
    }
  }
  float biasv0, biasv1;
  {
    int na = (tid & 31) * 2;
    biasv0 = bi[c * 64 + na] + bh[c * 64 + na];
    biasv1 = bi[c * 64 + na + 1] + bh[c * 64 + na + 1];
  }

  // A-group (layer0): emb prefetch for step 1 — 8 float4 per thread
  float4 pf0, pf1, pf2, pf3, pf4, pf5, pf6, pf7;
  if (layer == 0 && wid < 4) {
    int rid = x[(bg * 16 + gr) * SS + 0];
    const float4* ep = (const float4*)(emb + (size_t)rid * 512);
    pf0 = ep[2 * gch + 0];  pf1 = ep[2 * gch + 1];
    pf2 = ep[2 * gch + 32]; pf3 = ep[2 * gch + 33];
    pf4 = ep[2 * gch + 64]; pf5 = ep[2 * gch + 65];
    pf6 = ep[2 * gch + 96]; pf7 = ep[2 * gch + 97];
  }

  for (int s = 1; s <= SS; ++s) {
    const u32 exp_h = (u32)((s - 1) & 7);

    if (wid < 4) {
      // ================= A-group: in0 path =================
      if (layer == 0) {
        // stage emb (chunks gch+16j) from prefetch
        {
          i32x4 v;
          v[0] = pack2(f2bf(pf0.x), f2bf(pf0.y));
          v[1] = pack2(f2bf(pf0.z), f2bf(pf0.w));
          v[2] = pack2(f2bf(pf1.x), f2bf(pf1.y));
          v[3] = pack2(f2bf(pf1.z), f2bf(pf1.w));
          *(i32x4*)(s_in0 + gr * 512 + (((gch + 0) ^ (gr & 7)) << 3)) = v;
          v[0] = pack2(f2bf(pf2.x), f2bf(pf2.y));
          v[1] = pack2(f2bf(pf2.z), f2bf(pf2.w));
          v[2] = pack2(f2bf(pf3.x), f2bf(pf3.y));
          v[3] = pack2(f2bf(pf3.z), f2bf(pf3.w));
          *(i32x4*)(s_in0 + gr * 512 + (((gch + 16) ^ (gr & 7)) << 3)) = v;
          v[0] = pack2(f2bf(pf4.x), f2bf(pf4.y));
          v[1] = pack2(f2bf(pf4.z), f2bf(pf4.w));
          v[2] = pack2(f2bf(pf5.x), f2bf(pf5.y));
          v[3] = pack2(f2bf(pf5.z), f2bf(pf5.w));
          *(i32x4*)(s_in0 + gr * 512 + (((gch + 32) ^ (gr & 7)) << 3)) = v;
          v[0] = pack2(f2bf(pf6.x), f2bf(pf6.y));
          v[1] = pack2(f2bf(pf6.z), f2bf(pf6.w));
          v[2] = pack2(f2bf(pf7.x), f2bf(pf7.y));
          v[3] = pack2(f2bf(pf7.z), f2bf(pf7.w));
          *(i32x4*)(s_in0 + gr * 512 + (((gch + 48) ^ (gr & 7)) << 3)) = v;
        }
        // issue emb prefetch for s+1 (hides under barrier + MFMA + B-poll)
        if (s < SS) {
          int rid = x[(bg * 16 + gr) * SS + s];
          const float4* ep = (const float4*)(emb + (size_t)rid * 512);
          pf0 = ep[2 * gch + 0];  pf1 = ep[2 * gch + 1];
          pf2 = ep[2 * gch + 32]; pf3 = ep[2 * gch + 33];
          pf4 = ep[2 * gch + 64]; pf5 = ep[2 * gch + 65];
          pf6 = ep[2 * gch + 96]; pf7 = ep[2 * gch + 97];
        }
      } else {
        // layer1: pipelined 2-deep poll of in0[s] = out0[s]
        i32x4 x0 = {0,0,0,0}, x1 = {0,0,0,0}, x2 = {0,0,0,0}, x3 = {0,0,0,0};
        i32x4 x4 = {0,0,0,0}, x5 = {0,0,0,0}, x6 = {0,0,0,0}, x7 = {0,0,0,0};
        i32x4 y0 = {0,0,0,0}, y1 = {0,0,0,0}, y2 = {0,0,0,0}, y3 = {0,0,0,0};
        i32x4 y4 = {0,0,0,0}, y5 = {0,0,0,0}, y6 = {0,0,0,0}, y7 = {0,0,0,0};
        const u32 exp_i = (u32)(s & 7);
        const u32* pib =
            hsl + (((size_t)(s & 3)) * 64 + bg * 16 + gr) * 512;
        ISSUE8(x0, x1, x2, x3, x4, x5, x6, x7, pib);
        ISSUE8(y0, y1, y2, y3, y4, y5, y6, y7, pib);
        bool use_x;
        while (true) {
          asm volatile("s_waitcnt vmcnt(8)"
                       : "+v"(x0), "+v"(x1), "+v"(x2), "+v"(x3), "+v"(x4),
                         "+v"(x5), "+v"(x6), "+v"(x7)::"memory");
          if (__all(TAGOK8(x0, x1, x2, x3, x4, x5, x6, x7, exp_i))) {
            use_x = true;
            break;
          }
          ISSUE8(x0, x1, x2, x3, x4, x5, x6, x7, pib);
          asm volatile("s_waitcnt vmcnt(8)"
                       : "+v"(y0), "+v"(y1), "+v"(y2), "+v"(y3), "+v"(y4),
                         "+v"(y5), "+v"(y6), "+v"(y7)::"memory");
          if (__all(TAGOK8(y0, y1, y2, y3, y4, y5, y6, y7, exp_i))) {
            use_x = false;
            break;
          }
          ISSUE8(y0, y1, y2, y3, y4, y5, y6, y7, pib);
        }
        // drain the other batch before any register reuse
        asm volatile("s_waitcnt vmcnt(0)"
                     : "+v"(x0), "+v"(x1), "+v"(x2), "+v"(x3), "+v"(x4),
                       "+v"(x5), "+v"(x6), "+v"(x7), "+v"(y0), "+v"(y1),
                       "+v"(y2), "+v"(y3), "+v"(y4), "+v"(y5), "+v"(y6),
                       "+v"(y7)::"memory");
        if (use_x) {
          STAGE_IN0(x0, x1, x2, x3, x4, x5, x6, x7);
        } else {
          STAGE_IN0(y0, y1, y2, y3, y4, y5, y6, y7);
        }
      }
    } else {
      // ================= B-group: h[s-1] path (+bp for layer0) ===========
      if (s > 1) {
        i32x4 x0 = {0,0,0,0}, x1 = {0,0,0,0}, x2 = {0,0,0,0}, x3 = {0,0,0,0};
        i32x4 x4 = {0,0,0,0}, x5 = {0,0,0,0}, x6 = {0,0,0,0}, x7 = {0,0,0,0};
        i32x4 y0 = {0,0,0,0}, y1 = {0,0,0,0}, y2 = {0,0,0,0}, y3 = {0,0,0,0};
        i32x4 y4 = {0,0,0,0}, y5 = {0,0,0,0}, y6 = {0,0,0,0}, y7 = {0,0,0,0};
        const u32* phb = hsl +
            (((size_t)layer * 4 + ((s - 1) & 3)) * 64 + bg * 16 + gr) * 512;
        bool use_x;
        if (layer == 0) {
          const bool need_bp = (s > 4) && (gt < 8);
          const u32 exp_bp = (u32)((s - 4) & 7);
          const u32* pbp = hsl + ((size_t)(4 + ((s - 4) & 3)) * 64 + bg * 16) * 512 +
                           (gt < 8 ? gt * 64 : 0);
          u32 bpx = 0, bpy = 0;
          ISSUE8(x0, x1, x2, x3, x4, x5, x6, x7, phb);
          UC_LOAD1(bpx, pbp);
          ISSUE8(y0, y1, y2, y3, y4, y5, y6, y7, phb);
          UC_LOAD1(bpy, pbp);
          while (true) {
            asm volatile("s_waitcnt vmcnt(9)"
                         : "+v"(x0), "+v"(x1), "+v"(x2), "+v"(x3), "+v"(x4),
                           "+v"(x5), "+v"(x6), "+v"(x7), "+v"(bpx)::"memory");
            if (__all(TAGOK8(x0, x1, x2, x3, x4, x5, x6, x7, exp_h) &&
                      (!need_bp || ((bpx & 7u) == exp_bp)))) {
              use_x = true;
              break;
            }
            ISSUE8(x0, x1, x2, x3, x4, x5, x6, x7, phb);
            UC_LOAD1(bpx, pbp);
            asm volatile("s_waitcnt vmcnt(9)"
                         : "+v"(y0), "+v"(y1), "+v"(y2), "+v"(y3), "+v"(y4),
                           "+v"(y5), "+v"(y6), "+v"(y7), "+v"(bpy)::"memory");
            if (__all(TAGOK8(y0, y1, y2, y3, y4, y5, y6, y7, exp_h) &&
                      (!need_bp || ((bpy & 7u) == exp_bp)))) {
              use_x = false;
              break;
            }
            ISSUE8(y0, y1, y2, y3, y4, y5, y6, y7, phb);
            UC_LOAD1(bpy, pbp);
          }
          asm volatile("s_waitcnt vmcnt(0)"
                       : "+v"(x0), "+v"(x1), "+v"(x2), "+v"(x3), "+v"(x4),
                         "+v"(x5), "+v"(x6), "+v"(x7), "+v"(y0), "+v"(y1),
                         "+v"(y2), "+v"(y3), "+v"(y4), "+v"(y5), "+v"(y6),
                         "+v"(y7), "+v"(bpx), "+v"(bpy)::"memory");
        } else {
          ISSUE8(x0, x1, x2, x3, x4, x5, x6, x7, phb);
          ISSUE8(y0, y1, y2, y3, y4, y5, y6, y7, phb);
          while (true) {
            asm volatile("s_waitcnt vmcnt(8)"
                         : "+v"(x0), "+v"(x1), "+v"(x2), "+v"(x3), "+v"(x4),
                           "+v"(x5), "+v"(x6), "+v"(x7)::"memory");
            if (__all(TAGOK8(x0, x1, x2, x3, x4, x5, x6, x7, exp_h))) {
              use_x = true;
              break;
            }
            ISSUE8(x0, x1, x2, x3, x4, x5, x6, x7, phb);
            asm volatile("s_waitcnt vmcnt(8)"
                         : "+v"(y0), "+v"(y1), "+v"(y2), "+v"(y3), "+v"(y4),
                           "+v"(y5), "+v"(y6), "+v"(y7)::"memory");
            if (__all(TAGOK8(y0, y1, y2, y3, y4, y5, y6, y7, exp_h))) {
              use_x = false;
              break;
            }
            ISSUE8(y0, y1, y2, y3, y4, y5, y6, y7, phb);
          }
          asm volatile("s_waitcnt vmcnt(0)"
                       : "+v"(x0), "+v"(x1), "+v"(x2), "+v"(x3), "+v"(x4),
                         "+v"(x5), "+v"(x6), "+v"(x7), "+v"(y0), "+v"(y1),
                         "+v"(y2), "+v"(y3), "+v"(y4), "+v"(y5), "+v"(y6),
                         "+v"(y7)::"memory");
        }
        if (use_x) {
          STAGE_H(x0, x1, x2, x3, x4, x5, x6, x7);
        } else {
          STAGE_H(y0, y1, y2, y3, y4, y5, y6, y7);
        }
      }
    }
    __syncthreads();  // B1: s_in0 + s_H staged (A and B joined)

    // ---- full MFMA phase: all 8 waves, roles unchanged ----
    f32x4 acc0 = {0.f, 0.f, 0.f, 0.f};
    f32x4 acc1 = {0.f, 0.f, 0.f, 0.f};
    {
      const int r16 = lane & 15, kg = lane >> 4;
#pragma unroll
      for (int kt = 0; kt < 4; ++kt) {
        int k8 = kq * 16 + kt * 4 + kg;
        bf16x8 ain = __builtin_bit_cast(
            bf16x8, *(const i32x4*)(s_in0 + r16 * 512 + ((k8 ^ (r16 & 7)) << 3)));
        acc0 = __builtin_amdgcn_mfma_f32_16x16x32_bf16(ain, wih[0][kt], acc0, 0, 0, 0);
        acc1 = __builtin_amdgcn_mfma_f32_16x16x32_bf16(ain, wih[1][kt], acc1, 0, 0, 0);
      }
      if (s > 1) {
#pragma unroll
        for (int kt = 0; kt < 4; ++kt) {
          int k8 = kq * 16 + kt * 4 + kg;
          bf16x8 ahi = __builtin_bit_cast(
              bf16x8, *(const i32x4*)(s_Hhi + r16 * 512 + ((k8 ^ (r16 & 7)) << 3)));
          bf16x8 alo = __builtin_bit_cast(
              bf16x8, *(const i32x4*)(s_Hlo + r16 * 512 + ((k8 ^ (r16 & 7)) << 3)));
          acc0 = __builtin_amdgcn_mfma_f32_16x16x32_bf16(ahi, whhh[0][kt], acc0, 0, 0, 0);
          acc0 = __builtin_amdgcn_mfma_f32_16x16x32_bf16(ahi, whhl[0][kt], acc0, 0, 0, 0);
          acc0 = __builtin_amdgcn_mfma_f32_16x16x32_bf16(alo, whhh[0][kt], acc0, 0, 0, 0);
          acc1 = __builtin_amdgcn_mfma_f32_16x16x32_bf16(ahi, whhh[1][kt], acc1, 0, 0, 0);
          acc1 = __builtin_amdgcn_mfma_f32_16x16x32_bf16(ahi, whhl[1][kt], acc1, 0, 0, 0);
          acc1 = __builtin_amdgcn_mfma_f32_16x16x32_bf16(alo, whhh[1][kt], acc1, 0, 0, 0);
        }
      }
#pragma unroll
      for (int j = 0; j < 4; ++j) {
        int m = kg * 4 + j;
        int xr = (m >> 2) & 3;
        int n0i = nh * 32 + 0 * 16 + r16;
        int n1i = nh * 32 + 1 * 16 + r16;
        s_part[kq * 1024 + m * 64 + (n0i ^ (xr << 4))] = acc0[j];
        s_part[kq * 1024 + m * 64 + (n1i ^ (xr << 4))] = acc1[j];
      }
    }
    __syncthreads();  // B3

    // ---- finals: reduce, bias, fast-tanh, pack word (hi|lo|tag), publish ----
    {
      int m = tid >> 5, na = (tid & 31) * 2;
      int xr = (m >> 2) & 3;
      float v0 = biasv0, v1 = biasv1;
#pragma unroll
      for (int q2 = 0; q2 < 4; ++q2) {
        const float2* sp =
            (const float2*)(s_part + q2 * 1024 + m * 64 + (na ^ (xr << 4)));
        float2 t = *sp;
        v0 += t.x;
        v1 += t.y;
      }
      v0 = fast_tanh(v0);
      v1 = fast_tanh(v1);
      unsigned short a0 = f2bf(v0), a1 = f2bf(v1);
      unsigned short b0 = f2bf(v0 - bf2f(a0)), b1 = f2bf(v1 - bf2f(a1));
      u32 tag = (u32)(s & 7);
      u32x2 wv;
      wv[0] = ((u32)a0 << 16) | ((u32)b0 & 0xFFF8u) | tag;
      wv[1] = ((u32)a1 << 16) | ((u32)b1 & 0xFFF8u) | tag;
      u32* dst = hsl + (((size_t)layer * 4 + (s & 3)) * 64 + bg * 16 + m) * 512 +
                 c * 64 + na;
      UC_STORE2(dst, wv);
    }
    // no drain, no flag: consumers detect via embedded tags
  }
}

__global__ void k_fc(const u32* __restrict__ h1w, const float* __restrict__ fcW,
                     const float* __restrict__ fcb, float* __restrict__ out) {
  int i = threadIdx.x;  // 512 = 64 batch x 8 classes
  int b = i >> 3, cc = i & 7;
  float acc = fcb[cc];
  const u32* ph = h1w + b * 512;
  const float* pw = fcW + cc * 512;
  for (int k = 0; k < 512; k += 4) {
    int4 w4 = *(const int4*)(ph + k);
    float4 wv = *(const float4*)(pw + k);
    acc += (bf2f((unsigned short)((u32)w4.x >> 16)) +
            bf2f((unsigned short)((u32)w4.x & 0xFFF8u))) * wv.x;
    acc += (bf2f((unsigned short)((u32)w4.y >> 16)) +
            bf2f((unsigned short)((u32)w4.y & 0xFFF8u))) * wv.y;
    acc += (bf2f((unsigned short)((u32)w4.z >> 16)) +
            bf2f((unsigned short)((u32)w4.z & 0xFFF8u))) * wv.z;
    acc += (bf2f((unsigned short)((u32)w4.w >> 16)) +
            bf2f((unsigned short)((u32)w4.w & 0xFFF8u))) * wv.w;
  }
  out[b * 8 + cc] = acc;
}

extern "C" void kernel_launch(void* const* d_in, const int* in_sizes, int n_in,
                              void* d_out, int out_size, void* d_ws, size_t ws_size,
                              hipStream_t stream) {
  const int* x = (const int*)d_in[0];
  const float* emb = (const float*)d_in[1];
  const float* Wih0 = (const float*)d_in[2];
  const float* Whh0 = (const float*)d_in[3];
  const float* bih0 = (const float*)d_in[4];
  const float* bhh0 = (const float*)d_in[5];
  const float* Wih1 = (const float*)d_in[6];
  const float* Whh1 = (const float*)d_in[7];
  const float* bih1 = (const float*)d_in[8];
  const float* bhh1 = (const float*)d_in[9];
  const float* fcW = (const float*)d_in[10];
  const float* fcb = (const float*)d_in[11];

  u32* hsl = (u32*)d_ws;  // 2 layers x 4 slots x 64 x 512 u32 = 1 MB

  hipMemsetAsync(hsl, 0, (size_t)2 * 4 * 64 * 512 * 4, stream);
  hipLaunchKernelGGL(k_rnn, dim3(64), dim3(512), 0, stream, x, emb, Wih0, Whh0,
                     bih0, bhh0, Wih1, Whh1, bih1, bhh1, hsl);
  // final h1 = step 512 -> layer1 slot (512&3)==0
  hipLaunchKernelGGL(k_fc, dim3(1), dim3(512), 0, stream,
                     hsl + (size_t)4 * 64 * 512, fcW, fcb, (float*)d_out);
}

// Round 14
// 1880.580 us; speedup vs baseline: 1.0157x; 1.0157x over previous
//
#include <hip/hip_runtime.h>
#include <stdint.h>

// RNNTextClassifier: B=64, S=512, E=H=512, NCLS=8
// Round 17: R15 base (proven 1748us) + SENTINEL-then-BULK polling.
// R16 (2-deep pipelined poll) regressed +9% -> polls are CONTENTION-
// limited, not quantization-limited: each R15 round re-fetches 32 KB of
// device-scope data per 4-wave group just to read 3-bit tags, and FETCH
// (780MB >> 85MB explainable) shows the traffic reaches HBM. R17 splits
// detection from transfer:
//  1) sentinel loop: each lane polls ONE dword (row = wave 4-row span,
//     pub = lane&7) -> 2 KB/block/round, 32x less poll traffic. A
//     publisher's finals stores issue within ~cycles of its B3, so one
//     word per (row,pub) is a faithful readiness proxy.
//  2) bulk: issue R15's 8x dwordx4 once, verify ALL tags (correctness
//     still tag-guarded; straggler store -> rare bulk retry).
// bp folds into layer0's sentinel loop. Everything else byte-identical
// to R15: A/B wave split (A=in0, B=h), 256-thread stride-16 staging,
// ring slot=s&3, tag=s&7, bp at s-4, UC sc0 sc1, launch_bounds(512,1).
// ws: hsl 1MB at offset 0 (memset to 0 each launch).

#define BB 64
#define SS 512
#define HH 512

typedef short bf16x8 __attribute__((ext_vector_type(8)));
typedef float f32x4 __attribute__((ext_vector_type(4)));
typedef int i32x4 __attribute__((ext_vector_type(4)));
typedef unsigned int u32;
typedef u32 u32x2 __attribute__((ext_vector_type(2)));

__device__ __forceinline__ unsigned short f2bf(float f) {
  uint32_t u = __builtin_bit_cast(uint32_t, f);
  u += 0x7FFFu + ((u >> 16) & 1u);
  return (unsigned short)(u >> 16);
}
__device__ __forceinline__ float bf2f(unsigned short h) {
  uint32_t u = ((uint32_t)h) << 16;
  return __builtin_bit_cast(float, u);
}
__device__ __forceinline__ int pack2(unsigned short a, unsigned short b) {
  return (int)(unsigned int)a | ((int)(unsigned int)b << 16);
}
__device__ __forceinline__ u32 hipack(u32 a, u32 b) {
  return (a >> 16) | (b & 0xFFFF0000u);
}
__device__ __forceinline__ u32 lopack(u32 a, u32 b) {
  return (a & 0xFFF8u) | ((b & 0xFFF8u) << 16);
}
__device__ __forceinline__ bool tag4(i32x4 v, u32 t) {
  u32 m = (((u32)v[0] ^ t) | ((u32)v[1] ^ t) | ((u32)v[2] ^ t) | ((u32)v[3] ^ t)) & 7u;
  return m == 0u;
}
__device__ __forceinline__ float fast_tanh(float v) {
  float a = __builtin_fabsf(v);
  float e = __expf(-2.0f * a);
  float t = (1.0f - e) / (1.0f + e);
  return __builtin_copysignf(t, v);
}

#define UC_LOAD4(dst, ptr) \
  asm volatile("global_load_dwordx4 %0, %1, off sc0 sc1" : "=v"(dst) : "v"(ptr))
#define UC_LOAD1(dst, ptr) \
  asm volatile("global_load_dword %0, %1, off sc0 sc1" : "=v"(dst) : "v"(ptr))
#define UC_STORE2(ptr, v) \
  asm volatile("global_store_dwordx2 %0, %1, off sc0 sc1" ::"v"(ptr), "v"(v) : "memory")

// issue one 8x dwordx4 batch over the lane's 4 chunks (cols 8gch + 128q)
#define ISSUE8(a0, a1, a2, a3, a4, a5, a6, a7, base)  \
  do {                                                \
    UC_LOAD4(a0, (base) + 8 * gch + 0);               \
    UC_LOAD4(a1, (base) + 8 * gch + 4);               \
    UC_LOAD4(a2, (base) + 8 * gch + 128);             \
    UC_LOAD4(a3, (base) + 8 * gch + 132);             \
    UC_LOAD4(a4, (base) + 8 * gch + 256);             \
    UC_LOAD4(a5, (base) + 8 * gch + 260);             \
    UC_LOAD4(a6, (base) + 8 * gch + 384);             \
    UC_LOAD4(a7, (base) + 8 * gch + 388);             \
  } while (0)

#define TAGOK8(a0, a1, a2, a3, a4, a5, a6, a7, t)                         \
  (tag4(a0, t) && tag4(a1, t) && tag4(a2, t) && tag4(a3, t) &&            \
   tag4(a4, t) && tag4(a5, t) && tag4(a6, t) && tag4(a7, t))

// stage hi halves into swizzled s_in0 (chunks gch+16j)
#define STAGE_IN0(w0, w1, w2, w3, w4, w5, w6, w7)                          \
  do {                                                                     \
    i32x4 A;                                                               \
    A[0] = (int)hipack(w0[0], w0[1]); A[1] = (int)hipack(w0[2], w0[3]);    \
    A[2] = (int)hipack(w1[0], w1[1]); A[3] = (int)hipack(w1[2], w1[3]);    \
    *(i32x4*)(s_in0 + gr * 512 + (((gch + 0) ^ (gr & 7)) << 3)) = A;       \
    A[0] = (int)hipack(w2[0], w2[1]); A[1] = (int)hipack(w2[2], w2[3]);    \
    A[2] = (int)hipack(w3[0], w3[1]); A[3] = (int)hipack(w3[2], w3[3]);    \
    *(i32x4*)(s_in0 + gr * 512 + (((gch + 16) ^ (gr & 7)) << 3)) = A;      \
    A[0] = (int)hipack(w4[0], w4[1]); A[1] = (int)hipack(w4[2], w4[3]);    \
    A[2] = (int)hipack(w5[0], w5[1]); A[3] = (int)hipack(w5[2], w5[3]);    \
    *(i32x4*)(s_in0 + gr * 512 + (((gch + 32) ^ (gr & 7)) << 3)) = A;      \
    A[0] = (int)hipack(w6[0], w6[1]); A[1] = (int)hipack(w6[2], w6[3]);    \
    A[2] = (int)hipack(w7[0], w7[1]); A[3] = (int)hipack(w7[2], w7[3]);    \
    *(i32x4*)(s_in0 + gr * 512 + (((gch + 48) ^ (gr & 7)) << 3)) = A;      \
  } while (0)

// stage H hi/lo into swizzled s_Hhi/s_Hlo (chunks gch+16j)
#define STAGE_H(w0, w1, w2, w3, w4, w5, w6, w7)                            \
  do {                                                                     \
    i32x4 A, B;                                                            \
    A[0] = (int)hipack(w0[0], w0[1]); A[1] = (int)hipack(w0[2], w0[3]);    \
    A[2] = (int)hipack(w1[0], w1[1]); A[3] = (int)hipack(w1[2], w1[3]);    \
    B[0] = (int)lopack(w0[0], w0[1]); B[1] = (int)lopack(w0[2], w0[3]);    \
    B[2] = (int)lopack(w1[0], w1[1]); B[3] = (int)lopack(w1[2], w1[3]);    \
    *(i32x4*)(s_Hhi + gr * 512 + (((gch + 0) ^ (gr & 7)) << 3)) = A;       \
    *(i32x4*)(s_Hlo + gr * 512 + (((gch + 0) ^ (gr & 7)) << 3)) = B;       \
    A[0] = (int)hipack(w2[0], w2[1]); A[1] = (int)hipack(w2[2], w2[3]);    \
    A[2] = (int)hipack(w3[0], w3[1]); A[3] = (int)hipack(w3[2], w3[3]);    \
    B[0] = (int)lopack(w2[0], w2[1]); B[1] = (int)lopack(w2[2], w2[3]);    \
    B[2] = (int)lopack(w3[0], w3[1]); B[3] = (int)lopack(w3[2], w3[3]);    \
    *(i32x4*)(s_Hhi + gr * 512 + (((gch + 16) ^ (gr & 7)) << 3)) = A;      \
    *(i32x4*)(s_Hlo + gr * 512 + (((gch + 16) ^ (gr & 7)) << 3)) = B;      \
    A[0] = (int)hipack(w4[0], w4[1]); A[1] = (int)hipack(w4[2], w4[3]);    \
    A[2] = (int)hipack(w5[0], w5[1]); A[3] = (int)hipack(w5[2], w5[3]);    \
    B[0] = (int)lopack(w4[0], w4[1]); B[1] = (int)lopack(w4[2], w4[3]);    \
    B[2] = (int)lopack(w5[0], w5[1]); B[3] = (int)lopack(w5[2], w5[3]);    \
    *(i32x4*)(s_Hhi + gr * 512 + (((gch + 32) ^ (gr & 7)) << 3)) = A;      \
    *(i32x4*)(s_Hlo + gr * 512 + (((gch + 32) ^ (gr & 7)) << 3)) = B;      \
    A[0] = (int)hipack(w6[0], w6[1]); A[1] = (int)hipack(w6[2], w6[3]);    \
    A[2] = (int)hipack(w7[0], w7[1]); A[3] = (int)hipack(w7[2], w7[3]);    \
    B[0] = (int)lopack(w6[0], w6[1]); B[1] = (int)lopack(w6[2], w6[3]);    \
    B[2] = (int)lopack(w7[0], w7[1]); B[3] = (int)lopack(w7[2], w7[3]);    \
    *(i32x4*)(s_Hhi + gr * 512 + (((gch + 48) ^ (gr & 7)) << 3)) = A;      \
    *(i32x4*)(s_Hlo + gr * 512 + (((gch + 48) ^ (gr & 7)) << 3)) = B;      \
  } while (0)

__global__ __launch_bounds__(512, 1) void k_rnn(
    const int* __restrict__ x, const float* __restrict__ emb,
    const float* __restrict__ Wih0, const float* __restrict__ Whh0,
    const float* __restrict__ bih0, const float* __restrict__ bhh0,
    const float* __restrict__ Wih1, const float* __restrict__ Whh1,
    const float* __restrict__ bih1, const float* __restrict__ bhh1,
    u32* __restrict__ hsl) {
  const int tid = threadIdx.x;
  const int bid = blockIdx.x;
  const int layer = bid >> 5;  // 0 or 1
  const int lb = bid & 31;
  const int bg = lb >> 3;  // batch group (16 rows)
  const int c = lb & 7;    // hidden slice (64 dims)
  const int wid = tid >> 6;
  const int lane = tid & 63;
  const int kq = wid >> 1;  // K-quarter (0..3)
  const int nh = wid & 1;   // N-half (32 cols)
  // staging-group index: A = waves 0..3, B = waves 4..7
  const int gt = tid & 255;
  const int gr = gt >> 4;   // row 0..15
  const int gch = gt & 15;  // chunk-base 0..15
  // sentinel coords: each wave covers rows [(wid&3)*4, +4); lane polls
  // (row = wrow + (lane&31)>>3, pub = lane&7)  [lanes 32-63 duplicate]
  const int s_row = (wid & 3) * 4 + ((lane & 31) >> 3);
  const int s_pub = lane & 7;

  __shared__ __align__(16) unsigned short s_in0[16 * 512];
  __shared__ __align__(16) unsigned short s_Hhi[16 * 512];
  __shared__ __align__(16) unsigned short s_Hlo[16 * 512];
  __shared__ __align__(16) float s_part[4 * 16 * 64];

  const float* Wih = layer ? Wih1 : Wih0;
  const float* Whh = layer ? Whh1 : Whh0;
  const float* bi = layer ? bih1 : bih0;
  const float* bh = layer ? bhh1 : bhh0;

  // ---- one-time: W fragments into VGPRs (mapping unchanged from R8) ----
  bf16x8 wih[2][4], whhh[2][4], whhl[2][4];
  {
    const int r16 = lane & 15, kg = lane >> 4;
#pragma unroll
    for (int nt = 0; nt < 2; ++nt) {
#pragma unroll
      for (int kt = 0; kt < 4; ++kt) {
        int row = c * 64 + nh * 32 + nt * 16 + r16;
        int k0 = kq * 128 + kt * 32 + kg * 8;
        const float* p = Wih + row * 512 + k0;
        bf16x8 v;
#pragma unroll
        for (int j = 0; j < 8; ++j) v[j] = (short)f2bf(p[j]);
        wih[nt][kt] = v;
        const float* q = Whh + row * 512 + k0;
        bf16x8 vh, vl;
#pragma unroll
        for (int j = 0; j < 8; ++j) {
          float f = q[j];
          unsigned short h = f2bf(f);
          vh[j] = (short)h;
          vl[j] = (short)f2bf(f - bf2f(h));
        }
        whhh[nt][kt] = vh;
        whhl[nt][kt] = vl;
      }
    }
  }
  float biasv0, biasv1;
  {
    int na = (tid & 31) * 2;
    biasv0 = bi[c * 64 + na] + bh[c * 64 + na];
    biasv1 = bi[c * 64 + na + 1] + bh[c * 64 + na + 1];
  }

  // A-group (layer0): emb prefetch for step 1 — 8 float4 per thread
  float4 pf0, pf1, pf2, pf3, pf4, pf5, pf6, pf7;
  if (layer == 0 && wid < 4) {
    int rid = x[(bg * 16 + gr) * SS + 0];
    const float4* ep = (const float4*)(emb + (size_t)rid * 512);
    pf0 = ep[2 * gch + 0];  pf1 = ep[2 * gch + 1];
    pf2 = ep[2 * gch + 32]; pf3 = ep[2 * gch + 33];
    pf4 = ep[2 * gch + 64]; pf5 = ep[2 * gch + 65];
    pf6 = ep[2 * gch + 96]; pf7 = ep[2 * gch + 97];
  }

  for (int s = 1; s <= SS; ++s) {
    const u32 exp_h = (u32)((s - 1) & 7);

    if (wid < 4) {
      // ================= A-group: in0 path =================
      if (layer == 0) {
        // stage emb (chunks gch+16j) from prefetch
        {
          i32x4 v;
          v[0] = pack2(f2bf(pf0.x), f2bf(pf0.y));
          v[1] = pack2(f2bf(pf0.z), f2bf(pf0.w));
          v[2] = pack2(f2bf(pf1.x), f2bf(pf1.y));
          v[3] = pack2(f2bf(pf1.z), f2bf(pf1.w));
          *(i32x4*)(s_in0 + gr * 512 + (((gch + 0) ^ (gr & 7)) << 3)) = v;
          v[0] = pack2(f2bf(pf2.x), f2bf(pf2.y));
          v[1] = pack2(f2bf(pf2.z), f2bf(pf2.w));
          v[2] = pack2(f2bf(pf3.x), f2bf(pf3.y));
          v[3] = pack2(f2bf(pf3.z), f2bf(pf3.w));
          *(i32x4*)(s_in0 + gr * 512 + (((gch + 16) ^ (gr & 7)) << 3)) = v;
          v[0] = pack2(f2bf(pf4.x), f2bf(pf4.y));
          v[1] = pack2(f2bf(pf4.z), f2bf(pf4.w));
          v[2] = pack2(f2bf(pf5.x), f2bf(pf5.y));
          v[3] = pack2(f2bf(pf5.z), f2bf(pf5.w));
          *(i32x4*)(s_in0 + gr * 512 + (((gch + 32) ^ (gr & 7)) << 3)) = v;
          v[0] = pack2(f2bf(pf6.x), f2bf(pf6.y));
          v[1] = pack2(f2bf(pf6.z), f2bf(pf6.w));
          v[2] = pack2(f2bf(pf7.x), f2bf(pf7.y));
          v[3] = pack2(f2bf(pf7.z), f2bf(pf7.w));
          *(i32x4*)(s_in0 + gr * 512 + (((gch + 48) ^ (gr & 7)) << 3)) = v;
        }
        // issue emb prefetch for s+1 (hides under barrier + MFMA + B-poll)
        if (s < SS) {
          int rid = x[(bg * 16 + gr) * SS + s];
          const float4* ep = (const float4*)(emb + (size_t)rid * 512);
          pf0 = ep[2 * gch + 0];  pf1 = ep[2 * gch + 1];
          pf2 = ep[2 * gch + 32]; pf3 = ep[2 * gch + 33];
          pf4 = ep[2 * gch + 64]; pf5 = ep[2 * gch + 65];
          pf6 = ep[2 * gch + 96]; pf7 = ep[2 * gch + 97];
        }
      } else {
        // layer1: sentinel poll then bulk fetch of in0[s] = out0[s]
        const u32 exp_i = (u32)(s & 7);
        const u32* pib =
            hsl + (((size_t)(s & 3)) * 64 + bg * 16 + gr) * 512;
        {
          const u32* psent =
              hsl + (((size_t)(s & 3)) * 64 + bg * 16 + s_row) * 512 + s_pub * 64;
          u32 sw = 0;
          while (true) {
            UC_LOAD1(sw, psent);
            asm volatile("s_waitcnt vmcnt(0)" : "+v"(sw)::"memory");
            if (__all((sw & 7u) == exp_i)) break;
          }
        }
        i32x4 w0 = {0,0,0,0}, w1 = {0,0,0,0}, w2 = {0,0,0,0}, w3 = {0,0,0,0};
        i32x4 w4 = {0,0,0,0}, w5 = {0,0,0,0}, w6 = {0,0,0,0}, w7 = {0,0,0,0};
        while (true) {
          ISSUE8(w0, w1, w2, w3, w4, w5, w6, w7, pib);
          asm volatile("s_waitcnt vmcnt(0)"
                       : "+v"(w0), "+v"(w1), "+v"(w2), "+v"(w3), "+v"(w4),
                         "+v"(w5), "+v"(w6), "+v"(w7)::"memory");
          if (__all(TAGOK8(w0, w1, w2, w3, w4, w5, w6, w7, exp_i))) break;
        }
        STAGE_IN0(w0, w1, w2, w3, w4, w5, w6, w7);
      }
    } else {
      // ================= B-group: h[s-1] path (+bp for layer0) ===========
      if (s > 1) {
        const u32* phb = hsl +
            (((size_t)layer * 4 + ((s - 1) & 3)) * 64 + bg * 16 + gr) * 512;
        // sentinel loop (bp folded in for layer0)
        {
          const u32* psent = hsl +
              (((size_t)layer * 4 + ((s - 1) & 3)) * 64 + bg * 16 + s_row) * 512 +
              s_pub * 64;
          const bool need_bp = (layer == 0) && (s > 4);
          const u32 exp_bp = (u32)((s - 4) & 7);
          const u32* pbp = hsl + ((size_t)(4 + ((s - 4) & 3)) * 64 + bg * 16) * 512 +
                           s_pub * 64;
          u32 sw = 0, bw = 0;
          while (true) {
            UC_LOAD1(sw, psent);
            if (need_bp) UC_LOAD1(bw, pbp);
            asm volatile("s_waitcnt vmcnt(0)" : "+v"(sw), "+v"(bw)::"memory");
            bool ok = ((sw & 7u) == exp_h) && (!need_bp || ((bw & 7u) == exp_bp));
            if (__all(ok)) break;
          }
        }
        // bulk fetch + verify
        i32x4 w0 = {0,0,0,0}, w1 = {0,0,0,0}, w2 = {0,0,0,0}, w3 = {0,0,0,0};
        i32x4 w4 = {0,0,0,0}, w5 = {0,0,0,0}, w6 = {0,0,0,0}, w7 = {0,0,0,0};
        while (true) {
          ISSUE8(w0, w1, w2, w3, w4, w5, w6, w7, phb);
          asm volatile("s_waitcnt vmcnt(0)"
                       : "+v"(w0), "+v"(w1), "+v"(w2), "+v"(w3), "+v"(w4),
                         "+v"(w5), "+v"(w6), "+v"(w7)::"memory");
          if (__all(TAGOK8(w0, w1, w2, w3, w4, w5, w6, w7, exp_h))) break;
        }
        STAGE_H(w0, w1, w2, w3, w4, w5, w6, w7);
      }
    }
    __syncthreads();  // B1: s_in0 + s_H staged (A and B joined)

    // ---- full MFMA phase: all 8 waves, roles unchanged ----
    f32x4 acc0 = {0.f, 0.f, 0.f, 0.f};
    f32x4 acc1 = {0.f, 0.f, 0.f, 0.f};
    {
      const int r16 = lane & 15, kg = lane >> 4;
#pragma unroll
      for (int kt = 0; kt < 4; ++kt) {
        int k8 = kq * 16 + kt * 4 + kg;
        bf16x8 ain = __builtin_bit_cast(
            bf16x8, *(const i32x4*)(s_in0 + r16 * 512 + ((k8 ^ (r16 & 7)) << 3)));
        acc0 = __builtin_amdgcn_mfma_f32_16x16x32_bf16(ain, wih[0][kt], acc0, 0, 0, 0);
        acc1 = __builtin_amdgcn_mfma_f32_16x16x32_bf16(ain, wih[1][kt], acc1, 0, 0, 0);
      }
      if (s > 1) {
#pragma unroll
        for (int kt = 0; kt < 4; ++kt) {
          int k8 = kq * 16 + kt * 4 + kg;
          bf16x8 ahi = __builtin_bit_cast(
              bf16x8, *(const i32x4*)(s_Hhi + r16 * 512 + ((k8 ^ (r16 & 7)) << 3)));
          bf16x8 alo = __builtin_bit_cast(
              bf16x8, *(const i32x4*)(s_Hlo + r16 * 512 + ((k8 ^ (r16 & 7)) << 3)));
          acc0 = __builtin_amdgcn_mfma_f32_16x16x32_bf16(ahi, whhh[0][kt], acc0, 0, 0, 0);
          acc0 = __builtin_amdgcn_mfma_f32_16x16x32_bf16(ahi, whhl[0][kt], acc0, 0, 0, 0);
          acc0 = __builtin_amdgcn_mfma_f32_16x16x32_bf16(alo, whhh[0][kt], acc0, 0, 0, 0);
          acc1 = __builtin_amdgcn_mfma_f32_16x16x32_bf16(ahi, whhh[1][kt], acc1, 0, 0, 0);
          acc1 = __builtin_amdgcn_mfma_f32_16x16x32_bf16(ahi, whhl[1][kt], acc1, 0, 0, 0);
          acc1 = __builtin_amdgcn_mfma_f32_16x16x32_bf16(alo, whhh[1][kt], acc1, 0, 0, 0);
        }
      }
#pragma unroll
      for (int j = 0; j < 4; ++j) {
        int m = kg * 4 + j;
        int xr = (m >> 2) & 3;
        int n0i = nh * 32 + 0 * 16 + r16;
        int n1i = nh * 32 + 1 * 16 + r16;
        s_part[kq * 1024 + m * 64 + (n0i ^ (xr << 4))] = acc0[j];
        s_part[kq * 1024 + m * 64 + (n1i ^ (xr << 4))] = acc1[j];
      }
    }
    __syncthreads();  // B3

    // ---- finals: reduce, bias, fast-tanh, pack word (hi|lo|tag), publish ----
    {
      int m = tid >> 5, na = (tid & 31) * 2;
      int xr = (m >> 2) & 3;
      float v0 = biasv0, v1 = biasv1;
#pragma unroll
      for (int q2 = 0; q2 < 4; ++q2) {
        const float2* sp =
            (const float2*)(s_part + q2 * 1024 + m * 64 + (na ^ (xr << 4)));
        float2 t = *sp;
        v0 += t.x;
        v1 += t.y;
      }
      v0 = fast_tanh(v0);
      v1 = fast_tanh(v1);
      unsigned short a0 = f2bf(v0), a1 = f2bf(v1);
      unsigned short b0 = f2bf(v0 - bf2f(a0)), b1 = f2bf(v1 - bf2f(a1));
      u32 tag = (u32)(s & 7);
      u32x2 wv;
      wv[0] = ((u32)a0 << 16) | ((u32)b0 & 0xFFF8u) | tag;
      wv[1] = ((u32)a1 << 16) | ((u32)b1 & 0xFFF8u) | tag;
      u32* dst = hsl + (((size_t)layer * 4 + (s & 3)) * 64 + bg * 16 + m) * 512 +
                 c * 64 + na;
      UC_STORE2(dst, wv);
    }
    // no drain, no flag: consumers detect via embedded tags
  }
}

__global__ void k_fc(const u32* __restrict__ h1w, const float* __restrict__ fcW,
                     const float* __restrict__ fcb, float* __restrict__ out) {
  int i = threadIdx.x;  // 512 = 64 batch x 8 classes
  int b = i >> 3, cc = i & 7;
  float acc = fcb[cc];
  const u32* ph = h1w + b * 512;
  const float* pw = fcW + cc * 512;
  for (int k = 0; k < 512; k += 4) {
    int4 w4 = *(const int4*)(ph + k);
    float4 wv = *(const float4*)(pw + k);
    acc += (bf2f((unsigned short)((u32)w4.x >> 16)) +
            bf2f((unsigned short)((u32)w4.x & 0xFFF8u))) * wv.x;
    acc += (bf2f((unsigned short)((u32)w4.y >> 16)) +
            bf2f((unsigned short)((u32)w4.y & 0xFFF8u))) * wv.y;
    acc += (bf2f((unsigned short)((u32)w4.z >> 16)) +
            bf2f((unsigned short)((u32)w4.z & 0xFFF8u))) * wv.z;
    acc += (bf2f((unsigned short)((u32)w4.w >> 16)) +
            bf2f((unsigned short)((u32)w4.w & 0xFFF8u))) * wv.w;
  }
  out[b * 8 + cc] = acc;
}

extern "C" void kernel_launch(void* const* d_in, const int* in_sizes, int n_in,
                              void* d_out, int out_size, void* d_ws, size_t ws_size,
                              hipStream_t stream) {
  const int* x = (const int*)d_in[0];
  const float* emb = (const float*)d_in[1];
  const float* Wih0 = (const float*)d_in[2];
  const float* Whh0 = (const float*)d_in[3];
  const float* bih0 = (const float*)d_in[4];
  const float* bhh0 = (const float*)d_in[5];
  const float* Wih1 = (const float*)d_in[6];
  const float* Whh1 = (const float*)d_in[7];
  const float* bih1 = (const float*)d_in[8];
  const float* bhh1 = (const float*)d_in[9];
  const float* fcW = (const float*)d_in[10];
  const float* fcb = (const float*)d_in[11];

  u32* hsl = (u32*)d_ws;  // 2 layers x 4 slots x 64 x 512 u32 = 1 MB

  hipMemsetAsync(hsl, 0, (size_t)2 * 4 * 64 * 512 * 4, stream);
  hipLaunchKernelGGL(k_rnn, dim3(64), dim3(512), 0, stream, x, emb, Wih0, Whh0,
                     bih0, bhh0, Wih1, Whh1, bih1, bhh1, hsl);
  // final h1 = step 512 -> layer1 slot (512&3)==0
  hipLaunchKernelGGL(k_fc, dim3(1), dim3(512), 0, stream,
                     hsl + (size_t)4 * 64 * 512, fcW, fcb, (float*)d_out);
}

// Round 15
// 1718.783 us; speedup vs baseline: 1.1114x; 1.0941x over previous
//
#include <hip/hip_runtime.h>
#include <stdint.h>

// RNNTextClassifier: B=64, S=512, E=H=512, NCLS=8
// Round 18: R15 base (proven 1748us) + lightened critical B-spin.
// R16 (pipelined poll, +9%) and R17 (sentinel+bulk, +8%) both refuted:
// FETCH(780MB) = mandatory transfer, polls succeed ~first-try, and the
// fused detect+transfer single-RT spin of R15 is the right shape.
// R18 keeps R15 byte-identical except:
//  1) layer0's bp check moves from the B h-spin to the otherwise-idle
//     A-waves (own tiny 1-dword spin after emb staging). B's h-spin
//     loses 1 load+check per round; gating semantics unchanged (join B1).
//  2) s_setprio(1) around the B-group poll+stage (T5's regime — genuine
//     wave role-split now exists; B is the binding h-recurrence chain).
// Structure: A waves 0-3 = in0 path (layer0: stage emb + prefetch + bp;
// layer1: poll in0), B waves 4-7 = h[s-1] path. One barrier joins, all
// waves MFMA, s_part reduce, finals publish. Ring slot=s&3, tag=s&7,
// bp at s-4, UC sc0 sc1 device-scope, launch_bounds(512,1).
// ws: hsl 1MB at offset 0 (memset to 0 each launch).

#define BB 64
#define SS 512
#define HH 512

typedef short bf16x8 __attribute__((ext_vector_type(8)));
typedef float f32x4 __attribute__((ext_vector_type(4)));
typedef int i32x4 __attribute__((ext_vector_type(4)));
typedef unsigned int u32;
typedef u32 u32x2 __attribute__((ext_vector_type(2)));

__device__ __forceinline__ unsigned short f2bf(float f) {
  uint32_t u = __builtin_bit_cast(uint32_t, f);
  u += 0x7FFFu + ((u >> 16) & 1u);
  return (unsigned short)(u >> 16);
}
__device__ __forceinline__ float bf2f(unsigned short h) {
  uint32_t u = ((uint32_t)h) << 16;
  return __builtin_bit_cast(float, u);
}
__device__ __forceinline__ int pack2(unsigned short a, unsigned short b) {
  return (int)(unsigned int)a | ((int)(unsigned int)b << 16);
}
__device__ __forceinline__ u32 hipack(u32 a, u32 b) {
  return (a >> 16) | (b & 0xFFFF0000u);
}
__device__ __forceinline__ u32 lopack(u32 a, u32 b) {
  return (a & 0xFFF8u) | ((b & 0xFFF8u) << 16);
}
__device__ __forceinline__ bool tag4(i32x4 v, u32 t) {
  u32 m = (((u32)v[0] ^ t) | ((u32)v[1] ^ t) | ((u32)v[2] ^ t) | ((u32)v[3] ^ t)) & 7u;
  return m == 0u;
}
__device__ __forceinline__ float fast_tanh(float v) {
  float a = __builtin_fabsf(v);
  float e = __expf(-2.0f * a);
  float t = (1.0f - e) / (1.0f + e);
  return __builtin_copysignf(t, v);
}

#define UC_LOAD4(dst, ptr) \
  asm volatile("global_load_dwordx4 %0, %1, off sc0 sc1" : "=v"(dst) : "v"(ptr))
#define UC_LOAD1(dst, ptr) \
  asm volatile("global_load_dword %0, %1, off sc0 sc1" : "=v"(dst) : "v"(ptr))
#define UC_STORE2(ptr, v) \
  asm volatile("global_store_dwordx2 %0, %1, off sc0 sc1" ::"v"(ptr), "v"(v) : "memory")

// issue one 8x dwordx4 batch over the lane's 4 chunks (cols 8gch + 128q)
#define ISSUE8(a0, a1, a2, a3, a4, a5, a6, a7, base)  \
  do {                                                \
    UC_LOAD4(a0, (base) + 8 * gch + 0);               \
    UC_LOAD4(a1, (base) + 8 * gch + 4);               \
    UC_LOAD4(a2, (base) + 8 * gch + 128);             \
    UC_LOAD4(a3, (base) + 8 * gch + 132);             \
    UC_LOAD4(a4, (base) + 8 * gch + 256);             \
    UC_LOAD4(a5, (base) + 8 * gch + 260);             \
    UC_LOAD4(a6, (base) + 8 * gch + 384);             \
    UC_LOAD4(a7, (base) + 8 * gch + 388);             \
  } while (0)

#define TAGOK8(a0, a1, a2, a3, a4, a5, a6, a7, t)                         \
  (tag4(a0, t) && tag4(a1, t) && tag4(a2, t) && tag4(a3, t) &&            \
   tag4(a4, t) && tag4(a5, t) && tag4(a6, t) && tag4(a7, t))

// stage hi halves into swizzled s_in0 (chunks gch+16j)
#define STAGE_IN0(w0, w1, w2, w3, w4, w5, w6, w7)                          \
  do {                                                                     \
    i32x4 A;                                                               \
    A[0] = (int)hipack(w0[0], w0[1]); A[1] = (int)hipack(w0[2], w0[3]);    \
    A[2] = (int)hipack(w1[0], w1[1]); A[3] = (int)hipack(w1[2], w1[3]);    \
    *(i32x4*)(s_in0 + gr * 512 + (((gch + 0) ^ (gr & 7)) << 3)) = A;       \
    A[0] = (int)hipack(w2[0], w2[1]); A[1] = (int)hipack(w2[2], w2[3]);    \
    A[2] = (int)hipack(w3[0], w3[1]); A[3] = (int)hipack(w3[2], w3[3]);    \
    *(i32x4*)(s_in0 + gr * 512 + (((gch + 16) ^ (gr & 7)) << 3)) = A;      \
    A[0] = (int)hipack(w4[0], w4[1]); A[1] = (int)hipack(w4[2], w4[3]);    \
    A[2] = (int)hipack(w5[0], w5[1]); A[3] = (int)hipack(w5[2], w5[3]);    \
    *(i32x4*)(s_in0 + gr * 512 + (((gch + 32) ^ (gr & 7)) << 3)) = A;      \
    A[0] = (int)hipack(w6[0], w6[1]); A[1] = (int)hipack(w6[2], w6[3]);    \
    A[2] = (int)hipack(w7[0], w7[1]); A[3] = (int)hipack(w7[2], w7[3]);    \
    *(i32x4*)(s_in0 + gr * 512 + (((gch + 48) ^ (gr & 7)) << 3)) = A;      \
  } while (0)

// stage H hi/lo into swizzled s_Hhi/s_Hlo (chunks gch+16j)
#define STAGE_H(w0, w1, w2, w3, w4, w5, w6, w7)                            \
  do {                                                                     \
    i32x4 A, B;                                                            \
    A[0] = (int)hipack(w0[0], w0[1]); A[1] = (int)hipack(w0[2], w0[3]);    \
    A[2] = (int)hipack(w1[0], w1[1]); A[3] = (int)hipack(w1[2], w1[3]);    \
    B[0] = (int)lopack(w0[0], w0[1]); B[1] = (int)lopack(w0[2], w0[3]);    \
    B[2] = (int)lopack(w1[0], w1[1]); B[3] = (int)lopack(w1[2], w1[3]);    \
    *(i32x4*)(s_Hhi + gr * 512 + (((gch + 0) ^ (gr & 7)) << 3)) = A;       \
    *(i32x4*)(s_Hlo + gr * 512 + (((gch + 0) ^ (gr & 7)) << 3)) = B;       \
    A[0] = (int)hipack(w2[0], w2[1]); A[1] = (int)hipack(w2[2], w2[3]);    \
    A[2] = (int)hipack(w3[0], w3[1]); A[3] = (int)hipack(w3[2], w3[3]);    \
    B[0] = (int)lopack(w2[0], w2[1]); B[1] = (int)lopack(w2[2], w2[3]);    \
    B[2] = (int)lopack(w3[0], w3[1]); B[3] = (int)lopack(w3[2], w3[3]);    \
    *(i32x4*)(s_Hhi + gr * 512 + (((gch + 16) ^ (gr & 7)) << 3)) = A;      \
    *(i32x4*)(s_Hlo + gr * 512 + (((gch + 16) ^ (gr & 7)) << 3)) = B;      \
    A[0] = (int)hipack(w4[0], w4[1]); A[1] = (int)hipack(w4[2], w4[3]);    \
    A[2] = (int)hipack(w5[0], w5[1]); A[3] = (int)hipack(w5[2], w5[3]);    \
    B[0] = (int)lopack(w4[0], w4[1]); B[1] = (int)lopack(w4[2], w4[3]);    \
    B[2] = (int)lopack(w5[0], w5[1]); B[3] = (int)lopack(w5[2], w5[3]);    \
    *(i32x4*)(s_Hhi + gr * 512 + (((gch + 32) ^ (gr & 7)) << 3)) = A;      \
    *(i32x4*)(s_Hlo + gr * 512 + (((gch + 32) ^ (gr & 7)) << 3)) = B;      \
    A[0] = (int)hipack(w6[0], w6[1]); A[1] = (int)hipack(w6[2], w6[3]);    \
    A[2] = (int)hipack(w7[0], w7[1]); A[3] = (int)hipack(w7[2], w7[3]);    \
    B[0] = (int)lopack(w6[0], w6[1]); B[1] = (int)lopack(w6[2], w6[3]);    \
    B[2] = (int)lopack(w7[0], w7[1]); B[3] = (int)lopack(w7[2], w7[3]);    \
    *(i32x4*)(s_Hhi + gr * 512 + (((gch + 48) ^ (gr & 7)) << 3)) = A;      \
    *(i32x4*)(s_Hlo + gr * 512 + (((gch + 48) ^ (gr & 7)) << 3)) = B;      \
  } while (0)

__global__ __launch_bounds__(512, 1) void k_rnn(
    const int* __restrict__ x, const float* __restrict__ emb,
    const float* __restrict__ Wih0, const float* __restrict__ Whh0,
    const float* __restrict__ bih0, const float* __restrict__ bhh0,
    const float* __restrict__ Wih1, const float* __restrict__ Whh1,
    const float* __restrict__ bih1, const float* __restrict__ bhh1,
    u32* __restrict__ hsl) {
  const int tid = threadIdx.x;
  const int bid = blockIdx.x;
  const int layer = bid >> 5;  // 0 or 1
  const int lb = bid & 31;
  const int bg = lb >> 3;  // batch group (16 rows)
  const int c = lb & 7;    // hidden slice (64 dims)
  const int wid = tid >> 6;
  const int lane = tid & 63;
  const int kq = wid >> 1;  // K-quarter (0..3)
  const int nh = wid & 1;   // N-half (32 cols)
  // staging-group index: A = waves 0..3, B = waves 4..7
  const int gt = tid & 255;
  const int gr = gt >> 4;   // row 0..15
  const int gch = gt & 15;  // chunk-base 0..15 (chunks gch+16j, j=0..3)

  __shared__ __align__(16) unsigned short s_in0[16 * 512];
  __shared__ __align__(16) unsigned short s_Hhi[16 * 512];
  __shared__ __align__(16) unsigned short s_Hlo[16 * 512];
  __shared__ __align__(16) float s_part[4 * 16 * 64];

  const float* Wih = layer ? Wih1 : Wih0;
  const float* Whh = layer ? Whh1 : Whh0;
  const float* bi = layer ? bih1 : bih0;
  const float* bh = layer ? bhh1 : bhh0;

  // ---- one-time: W fragments into VGPRs (mapping unchanged from R8) ----
  bf16x8 wih[2][4], whhh[2][4], whhl[2][4];
  {
    const int r16 = lane & 15, kg = lane >> 4;
#pragma unroll
    for (int nt = 0; nt < 2; ++nt) {
#pragma unroll
      for (int kt = 0; kt < 4; ++kt) {
        int row = c * 64 + nh * 32 + nt * 16 + r16;
        int k0 = kq * 128 + kt * 32 + kg * 8;
        const float* p = Wih + row * 512 + k0;
        bf16x8 v;
#pragma unroll
        for (int j = 0; j < 8; ++j) v[j] = (short)f2bf(p[j]);
        wih[nt][kt] = v;
        const float* q = Whh + row * 512 + k0;
        bf16x8 vh, vl;
#pragma unroll
        for (int j = 0; j < 8; ++j) {
          float f = q[j];
          unsigned short h = f2bf(f);
          vh[j] = (short)h;
          vl[j] = (short)f2bf(f - bf2f(h));
        }
        whhh[nt][kt] = vh;
        whhl[nt][kt] = vl;
      }
    }
  }
  float biasv0, biasv1;
  {
    int na = (tid & 31) * 2;
    biasv0 = bi[c * 64 + na] + bh[c * 64 + na];
    biasv1 = bi[c * 64 + na + 1] + bh[c * 64 + na + 1];
  }

  // A-group (layer0): emb prefetch for step 1 — 8 float4 per thread
  float4 pf0, pf1, pf2, pf3, pf4, pf5, pf6, pf7;
  if (layer == 0 && wid < 4) {
    int rid = x[(bg * 16 + gr) * SS + 0];
    const float4* ep = (const float4*)(emb + (size_t)rid * 512);
    pf0 = ep[2 * gch + 0];  pf1 = ep[2 * gch + 1];
    pf2 = ep[2 * gch + 32]; pf3 = ep[2 * gch + 33];
    pf4 = ep[2 * gch + 64]; pf5 = ep[2 * gch + 65];
    pf6 = ep[2 * gch + 96]; pf7 = ep[2 * gch + 97];
  }

  for (int s = 1; s <= SS; ++s) {
    const u32 exp_h = (u32)((s - 1) & 7);

    if (wid < 4) {
      // ================= A-group: in0 path =================
      if (layer == 0) {
        // stage emb (chunks gch+16j) from prefetch
        {
          i32x4 v;
          v[0] = pack2(f2bf(pf0.x), f2bf(pf0.y));
          v[1] = pack2(f2bf(pf0.z), f2bf(pf0.w));
          v[2] = pack2(f2bf(pf1.x), f2bf(pf1.y));
          v[3] = pack2(f2bf(pf1.z), f2bf(pf1.w));
          *(i32x4*)(s_in0 + gr * 512 + (((gch + 0) ^ (gr & 7)) << 3)) = v;
          v[0] = pack2(f2bf(pf2.x), f2bf(pf2.y));
          v[1] = pack2(f2bf(pf2.z), f2bf(pf2.w));
          v[2] = pack2(f2bf(pf3.x), f2bf(pf3.y));
          v[3] = pack2(f2bf(pf3.z), f2bf(pf3.w));
          *(i32x4*)(s_in0 + gr * 512 + (((gch + 16) ^ (gr & 7)) << 3)) = v;
          v[0] = pack2(f2bf(pf4.x), f2bf(pf4.y));
          v[1] = pack2(f2bf(pf4.z), f2bf(pf4.w));
          v[2] = pack2(f2bf(pf5.x), f2bf(pf5.y));
          v[3] = pack2(f2bf(pf5.z), f2bf(pf5.w));
          *(i32x4*)(s_in0 + gr * 512 + (((gch + 32) ^ (gr & 7)) << 3)) = v;
          v[0] = pack2(f2bf(pf6.x), f2bf(pf6.y));
          v[1] = pack2(f2bf(pf6.z), f2bf(pf6.w));
          v[2] = pack2(f2bf(pf7.x), f2bf(pf7.y));
          v[3] = pack2(f2bf(pf7.z), f2bf(pf7.w));
          *(i32x4*)(s_in0 + gr * 512 + (((gch + 48) ^ (gr & 7)) << 3)) = v;
        }
        // issue emb prefetch for s+1 (hides under barrier + MFMA + B-poll)
        if (s < SS) {
          int rid = x[(bg * 16 + gr) * SS + s];
          const float4* ep = (const float4*)(emb + (size_t)rid * 512);
          pf0 = ep[2 * gch + 0];  pf1 = ep[2 * gch + 1];
          pf2 = ep[2 * gch + 32]; pf3 = ep[2 * gch + 33];
          pf4 = ep[2 * gch + 64]; pf5 = ep[2 * gch + 65];
          pf6 = ep[2 * gch + 96]; pf7 = ep[2 * gch + 97];
        }
        // bp check on idle A-waves: layer1 must have consumed slot s-4
        if (s > 4) {
          const u32 exp_bp = (u32)((s - 4) & 7);
          const u32* pbp = hsl + ((size_t)(4 + ((s - 4) & 3)) * 64 + bg * 16) * 512 +
                           (gt < 8 ? gt * 64 : 0);
          u32 bw = 0;
          while (true) {
            UC_LOAD1(bw, pbp);
            asm volatile("s_waitcnt vmcnt(0)" : "+v"(bw)::"memory");
            if (__all(gt >= 8 || ((bw & 7u) == exp_bp))) break;
          }
        }
      } else {
        // layer1: poll in0[s] = out0[s] (fused detect+transfer spin)
        i32x4 w0 = {0,0,0,0}, w1 = {0,0,0,0}, w2 = {0,0,0,0}, w3 = {0,0,0,0};
        i32x4 w4 = {0,0,0,0}, w5 = {0,0,0,0}, w6 = {0,0,0,0}, w7 = {0,0,0,0};
        const u32 exp_i = (u32)(s & 7);
        const u32* pib =
            hsl + (((size_t)(s & 3)) * 64 + bg * 16 + gr) * 512;
        while (true) {
          ISSUE8(w0, w1, w2, w3, w4, w5, w6, w7, pib);
          asm volatile("s_waitcnt vmcnt(0)"
                       : "+v"(w0), "+v"(w1), "+v"(w2), "+v"(w3), "+v"(w4),
                         "+v"(w5), "+v"(w6), "+v"(w7)::"memory");
          if (__all(TAGOK8(w0, w1, w2, w3, w4, w5, w6, w7, exp_i))) break;
        }
        STAGE_IN0(w0, w1, w2, w3, w4, w5, w6, w7);
      }
    } else {
      // ================= B-group: h[s-1] path (pure h spin) =============
      if (s > 1) {
        __builtin_amdgcn_s_setprio(1);
        i32x4 w0 = {0,0,0,0}, w1 = {0,0,0,0}, w2 = {0,0,0,0}, w3 = {0,0,0,0};
        i32x4 w4 = {0,0,0,0}, w5 = {0,0,0,0}, w6 = {0,0,0,0}, w7 = {0,0,0,0};
        const u32* phb = hsl +
            (((size_t)layer * 4 + ((s - 1) & 3)) * 64 + bg * 16 + gr) * 512;
        while (true) {
          ISSUE8(w0, w1, w2, w3, w4, w5, w6, w7, phb);
          asm volatile("s_waitcnt vmcnt(0)"
                       : "+v"(w0), "+v"(w1), "+v"(w2), "+v"(w3), "+v"(w4),
                         "+v"(w5), "+v"(w6), "+v"(w7)::"memory");
          if (__all(TAGOK8(w0, w1, w2, w3, w4, w5, w6, w7, exp_h))) break;
        }
        STAGE_H(w0, w1, w2, w3, w4, w5, w6, w7);
        __builtin_amdgcn_s_setprio(0);
      }
    }
    __syncthreads();  // B1: s_in0 + s_H staged (A and B joined; bp enforced)

    // ---- full MFMA phase: all 8 waves, roles unchanged ----
    f32x4 acc0 = {0.f, 0.f, 0.f, 0.f};
    f32x4 acc1 = {0.f, 0.f, 0.f, 0.f};
    {
      const int r16 = lane & 15, kg = lane >> 4;
#pragma unroll
      for (int kt = 0; kt < 4; ++kt) {
        int k8 = kq * 16 + kt * 4 + kg;
        bf16x8 ain = __builtin_bit_cast(
            bf16x8, *(const i32x4*)(s_in0 + r16 * 512 + ((k8 ^ (r16 & 7)) << 3)));
        acc0 = __builtin_amdgcn_mfma_f32_16x16x32_bf16(ain, wih[0][kt], acc0, 0, 0, 0);
        acc1 = __builtin_amdgcn_mfma_f32_16x16x32_bf16(ain, wih[1][kt], acc1, 0, 0, 0);
      }
      if (s > 1) {
#pragma unroll
        for (int kt = 0; kt < 4; ++kt) {
          int k8 = kq * 16 + kt * 4 + kg;
          bf16x8 ahi = __builtin_bit_cast(
              bf16x8, *(const i32x4*)(s_Hhi + r16 * 512 + ((k8 ^ (r16 & 7)) << 3)));
          bf16x8 alo = __builtin_bit_cast(
              bf16x8, *(const i32x4*)(s_Hlo + r16 * 512 + ((k8 ^ (r16 & 7)) << 3)));
          acc0 = __builtin_amdgcn_mfma_f32_16x16x32_bf16(ahi, whhh[0][kt], acc0, 0, 0, 0);
          acc0 = __builtin_amdgcn_mfma_f32_16x16x32_bf16(ahi, whhl[0][kt], acc0, 0, 0, 0);
          acc0 = __builtin_amdgcn_mfma_f32_16x16x32_bf16(alo, whhh[0][kt], acc0, 0, 0, 0);
          acc1 = __builtin_amdgcn_mfma_f32_16x16x32_bf16(ahi, whhh[1][kt], acc1, 0, 0, 0);
          acc1 = __builtin_amdgcn_mfma_f32_16x16x32_bf16(ahi, whhl[1][kt], acc1, 0, 0, 0);
          acc1 = __builtin_amdgcn_mfma_f32_16x16x32_bf16(alo, whhh[1][kt], acc1, 0, 0, 0);
        }
      }
#pragma unroll
      for (int j = 0; j < 4; ++j) {
        int m = kg * 4 + j;
        int xr = (m >> 2) & 3;
        int n0i = nh * 32 + 0 * 16 + r16;
        int n1i = nh * 32 + 1 * 16 + r16;
        s_part[kq * 1024 + m * 64 + (n0i ^ (xr << 4))] = acc0[j];
        s_part[kq * 1024 + m * 64 + (n1i ^ (xr << 4))] = acc1[j];
      }
    }
    __syncthreads();  // B3

    // ---- finals: reduce, bias, fast-tanh, pack word (hi|lo|tag), publish ----
    {
      int m = tid >> 5, na = (tid & 31) * 2;
      int xr = (m >> 2) & 3;
      float v0 = biasv0, v1 = biasv1;
#pragma unroll
      for (int q2 = 0; q2 < 4; ++q2) {
        const float2* sp =
            (const float2*)(s_part + q2 * 1024 + m * 64 + (na ^ (xr << 4)));
        float2 t = *sp;
        v0 += t.x;
        v1 += t.y;
      }
      v0 = fast_tanh(v0);
      v1 = fast_tanh(v1);
      unsigned short a0 = f2bf(v0), a1 = f2bf(v1);
      unsigned short b0 = f2bf(v0 - bf2f(a0)), b1 = f2bf(v1 - bf2f(a1));
      u32 tag = (u32)(s & 7);
      u32x2 wv;
      wv[0] = ((u32)a0 << 16) | ((u32)b0 & 0xFFF8u) | tag;
      wv[1] = ((u32)a1 << 16) | ((u32)b1 & 0xFFF8u) | tag;
      u32* dst = hsl + (((size_t)layer * 4 + (s & 3)) * 64 + bg * 16 + m) * 512 +
                 c * 64 + na;
      UC_STORE2(dst, wv);
    }
    // no drain, no flag: consumers detect via embedded tags
  }
}

__global__ void k_fc(const u32* __restrict__ h1w, const float* __restrict__ fcW,
                     const float* __restrict__ fcb, float* __restrict__ out) {
  int i = threadIdx.x;  // 512 = 64 batch x 8 classes
  int b = i >> 3, cc = i & 7;
  float acc = fcb[cc];
  const u32* ph = h1w + b * 512;
  const float* pw = fcW + cc * 512;
  for (int k = 0; k < 512; k += 4) {
    int4 w4 = *(const int4*)(ph + k);
    float4 wv = *(const float4*)(pw + k);
    acc += (bf2f((unsigned short)((u32)w4.x >> 16)) +
            bf2f((unsigned short)((u32)w4.x & 0xFFF8u))) * wv.x;
    acc += (bf2f((unsigned short)((u32)w4.y >> 16)) +
            bf2f((unsigned short)((u32)w4.y & 0xFFF8u))) * wv.y;
    acc += (bf2f((unsigned short)((u32)w4.z >> 16)) +
            bf2f((unsigned short)((u32)w4.z & 0xFFF8u))) * wv.z;
    acc += (bf2f((unsigned short)((u32)w4.w >> 16)) +
            bf2f((unsigned short)((u32)w4.w & 0xFFF8u))) * wv.w;
  }
  out[b * 8 + cc] = acc;
}

extern "C" void kernel_launch(void* const* d_in, const int* in_sizes, int n_in,
                              void* d_out, int out_size, void* d_ws, size_t ws_size,
                              hipStream_t stream) {
  const int* x = (const int*)d_in[0];
  const float* emb = (const float*)d_in[1];
  const float* Wih0 = (const float*)d_in[2];
  const float* Whh0 = (const float*)d_in[3];
  const float* bih0 = (const float*)d_in[4];
  const float* bhh0 = (const float*)d_in[5];
  const float* Wih1 = (const float*)d_in[6];
  const float* Whh1 = (const float*)d_in[7];
  const float* bih1 = (const float*)d_in[8];
  const float* bhh1 = (const float*)d_in[9];
  const float* fcW = (const float*)d_in[10];
  const float* fcb = (const float*)d_in[11];

  u32* hsl = (u32*)d_ws;  // 2 layers x 4 slots x 64 x 512 u32 = 1 MB

  hipMemsetAsync(hsl, 0, (size_t)2 * 4 * 64 * 512 * 4, stream);
  hipLaunchKernelGGL(k_rnn, dim3(64), dim3(512), 0, stream, x, emb, Wih0, Whh0,
                     bih0, bhh0, Wih1, Whh1, bih1, bhh1, hsl);
  // final h1 = step 512 -> layer1 slot (512&3)==0
  hipLaunchKernelGGL(k_fc, dim3(1), dim3(512), 0, stream,
                     hsl + (size_t)4 * 64 * 512, fcW, fcb, (float*)d_out);
}